// Round 2
// baseline (669.219 us; speedup 1.0000x reference)
//
#include <hip/hip_runtime.h>
#include <hip/hip_bf16.h>
#include <cstdint>

// Problem constants
#define BB 4
#define TT 2048
#define EE 1024
#define HH 16
#define DD 64
#define BH (BB*HH)       // 64
#define MM (BB*TT)       // 8192 rows for projection GEMMs
#define KK 1024          // contraction dim for projections
#define KSTR 72          // flash K-tile LDS row stride (ushorts)
#define VSTR 136         // flash V-tile LDS row stride (ushorts)
#define LOG2E 1.44269504088896340736f

typedef __attribute__((ext_vector_type(8))) short short8;    // 8 x bf16
typedef __attribute__((ext_vector_type(4))) short short4_;   // 4 x bf16
typedef __attribute__((ext_vector_type(4))) float float4_;   // MFMA accumulator
typedef __attribute__((ext_vector_type(4))) ushort ushort4_;

__device__ __forceinline__ void gl_lds16(const void* g, void* l) {
    __builtin_amdgcn_global_load_lds(
        (const __attribute__((address_space(1))) void*)g,
        (__attribute__((address_space(3))) void*)l, 16, 0, 0);
}

__device__ __forceinline__ ushort f2bf(float v) {
    __hip_bfloat16 h = __float2bfloat16(v);
    return *(ushort*)&h;
}

// ---------------------------------------------------------------------------
// fp32 -> bf16 conversion. grid.y selects segment (ptr,n); oversized grid.x
// blocks for short segments exit early.
// ---------------------------------------------------------------------------
__global__ __launch_bounds__(256) void cvt_kernel(
    const float* __restrict__ s0, ushort* __restrict__ d0, int n0,
    const float* __restrict__ s1, ushort* __restrict__ d1, int n1,
    const float* __restrict__ s2, ushort* __restrict__ d2, int n2,
    const float* __restrict__ s3, ushort* __restrict__ d3, int n3)
{
    const float* s; ushort* d; int n;
    switch (blockIdx.y) {
        case 0: s = s0; d = d0; n = n0; break;
        case 1: s = s1; d = d1; n = n1; break;
        case 2: s = s2; d = d2; n = n2; break;
        default: s = s3; d = d3; n = n3; break;
    }
    int i = (blockIdx.x * 256 + threadIdx.x) * 4;
    if (i >= n) return;
    float4_ v = *(const float4_*)&s[i];
    ushort4_ o;
#pragma unroll
    for (int j = 0; j < 4; j++) o[j] = f2bf(v[j]);
    *(ushort4_*)&d[i] = o;
}

// ---------------------------------------------------------------------------
// Pure-bf16 NT GEMM (m97 structure): C[n,e] = (sum_k A[n,k]*W[e,k] + bias[e])*scale
// MODE 0: C fp32 row-major [MM, EE]
// MODE 1: scatter bf16 per-head [B*H, T, D]
// MODE 2: scatter bf16 per-head transposed [B*H, D, T] (packed 8B stores)
// 128x128 tile, BK=32, 256 threads (4 waves, 2x2 of 64x64).
// ---------------------------------------------------------------------------
template<int MODE>
__global__ __launch_bounds__(256, 3) void gemm_nt(
    const ushort* __restrict__ A, const ushort* __restrict__ W,
    const float* __restrict__ bias, void* __restrict__ Cout, float scale)
{
    __shared__ __align__(16) ushort As[128*32];
    __shared__ __align__(16) ushort Bs[128*32];

    const int tid  = threadIdx.x;
    const int wave = tid >> 6;
    const int lane = tid & 63;
    const int l15  = lane & 15;
    const int quad = lane >> 4;
    const int wm   = wave & 1;   // row half
    const int wn   = wave >> 1;  // col half

    const long rowBase = (long)blockIdx.y * 128;
    const long colBase = (long)blockIdx.x * 128;

    float4_ acc[4][4];
#pragma unroll
    for (int i = 0; i < 4; i++)
#pragma unroll
        for (int j = 0; j < 4; j++) acc[i][j] = float4_{0.f, 0.f, 0.f, 0.f};

    for (int k0 = 0; k0 < KK; k0 += 32) {
        __syncthreads();
#pragma unroll
        for (int it = 0; it < 2; it++) {
            int idx = it * 256 + tid;          // 0..511
            int r   = idx >> 2;                // tile row 0..127
            int c8  = (idx & 3) * 8;           // k chunk (8 bf16 = 16B)
            gl_lds16(A + (rowBase + r) * KK + k0 + c8, &As[idx * 8]);
            gl_lds16(W + (colBase + r) * KK + k0 + c8, &Bs[idx * 8]);
        }
        __syncthreads();

        short8 af[4], bf[4];
#pragma unroll
        for (int mt = 0; mt < 4; mt++)
            af[mt] = *(const short8*)&As[(wm*64 + mt*16 + l15) * 32 + quad*8];
#pragma unroll
        for (int nt = 0; nt < 4; nt++)
            bf[nt] = *(const short8*)&Bs[(wn*64 + nt*16 + l15) * 32 + quad*8];
#pragma unroll
        for (int mt = 0; mt < 4; mt++)
#pragma unroll
            for (int nt = 0; nt < 4; nt++)
                acc[mt][nt] = __builtin_amdgcn_mfma_f32_16x16x32_bf16(
                    af[mt], bf[nt], acc[mt][nt], 0, 0, 0);
    }

    // Epilogue: C/D layout col = lane&15, row = quad*4 + reg
#pragma unroll
    for (int nt = 0; nt < 4; nt++) {
        const long col = colBase + wn*64 + nt*16 + l15;
        const float bv = bias[col];
#pragma unroll
        for (int mt = 0; mt < 4; mt++) {
            const long row0 = rowBase + wm*64 + mt*16 + quad*4;
            if (MODE == 2) {
                const long h = col >> 6, d = col & (DD - 1);
                const long b = row0 >> 11, t0 = row0 & (TT - 1);
                ushort4_ pk;
#pragma unroll
                for (int i = 0; i < 4; i++) pk[i] = f2bf((acc[mt][nt][i] + bv) * scale);
                *(ushort4_*)((ushort*)Cout + ((b*HH + h)*DD + d)*TT + t0) = pk;
            } else {
#pragma unroll
                for (int i = 0; i < 4; i++) {
                    const long row = row0 + i;
                    const float v = (acc[mt][nt][i] + bv) * scale;
                    if (MODE == 0) {
                        ((float*)Cout)[row * EE + col] = v;
                    } else {
                        const long b = row >> 11, t = row & (TT - 1);
                        const long h = col >> 6,  d = col & (DD - 1);
                        ((ushort*)Cout)[(((b*HH + h) * TT) + t) * DD + d] = f2bf(v);
                    }
                }
            }
        }
    }
}

// ---------------------------------------------------------------------------
// Flash attention (causal). Q,K: [B*H, T, D] bf16; Vt: [B*H, D, T] bf16;
// AO: [B, T, E] bf16.  Q pre-scaled by 0.125*log2(e) -> softmax via exp2.
//
// Operand-swapped layout: S^T = mfma(K, Q) -> lane owns 32 keys of ONE q-row
// (scalar softmax state, 2 shfls per reduction).
//
// NEW this round: P stays ENTIRELY in registers. The PV contraction's
// k-slot -> key mapping is arbitrary as long as the V (A-frag) and P (B-frag)
// use the SAME mapping.  Choose: chunk c covers keys nt in {2c, 2c+1}, with
// k-slot (quad, j) -> key (2c + (j>>2))*16 + quad*4 + (j&3).  Then the B-frag
// is a pure register repack of this lane's own s[2c][*], s[2c+1][*] (8 f2bf,
// no cross-lane, no LDS), and the V A-frag is two ds_read_b64 per output
// tile.  This deletes the 34.8 KB Ps buffer -> LDS 35.8 KB -> 4 blocks/CU
// (16 -> 32 resident waves), and removes the P round-trip + fence from the
// serial path.
// ---------------------------------------------------------------------------
__global__ __launch_bounds__(512, 8) void flash_kernel(
    const ushort* __restrict__ Qh, const ushort* __restrict__ Kh,
    const ushort* __restrict__ Vt, ushort* __restrict__ AO)
{
    __shared__ __align__(16) ushort Ks[128*KSTR];    // [key][d]     18.4 KB
    __shared__ __align__(16) ushort Vs[64*VSTR];     // [d][key]     17.4 KB

    const int qt  = (TT/128 - 1) - blockIdx.x;  // heavy tiles dispatch first
    const int bh  = blockIdx.y;                 // b*H + h
    const int tid = threadIdx.x;
    const int wave = tid >> 6, lane = tid & 63;
    const int l15 = lane & 15, quad = lane >> 4;

    const ushort* Qb = Qh + (long)bh * TT * DD;
    const ushort* Kb = Kh + (long)bh * TT * DD;
    const ushort* Vb = Vt + (long)bh * DD * TT;

    // This lane's q-row (B-fragment of swapped QK^T; also the output t)
    const int qrow = qt*128 + wave*16 + l15;
    short8 aq0 = *(const short8*)&Qb[(long)qrow * DD + quad*8];
    short8 aq1 = *(const short8*)&Qb[(long)qrow * DD + 32 + quad*8];

    // O^T accumulator: o[nt][i] = O[q=qrow][d = nt*16 + quad*4 + i]
    float4_ o[4];
#pragma unroll
    for (int nt = 0; nt < 4; nt++) o[nt] = float4_{0.f, 0.f, 0.f, 0.f};
    float m_run = -INFINITY, l_run = 0.0f;      // scalar per lane (one q-row)

    const int nkt = qt + 1;                    // number of 128-key tiles

    // prefetch tile 0 into registers (K: 128x64, V^T: 64x128)
    short8 kreg[2], vreg[2];
#pragma unroll
    for (int it = 0; it < 2; it++) {
        int c = it * 512 + tid;                    // 0..1023
        int kk = c >> 3, ks = c & 7;               // K: key, 16B seg
        kreg[it] = *(const short8*)&Kb[(long)kk * DD + ks*8];
        int dd = c >> 4, vs = c & 15;              // V: d, 16B seg
        vreg[it] = *(const short8*)&Vb[(long)dd * TT + vs*8];
    }

    for (int kt = 0; kt < nkt; kt++) {
        __syncthreads();   // previous tile's LDS reads done
#pragma unroll
        for (int it = 0; it < 2; it++) {
            int c = it * 512 + tid;
            int kk = c >> 3, ks = c & 7;
            *(short8*)&Ks[kk*KSTR + ks*8] = kreg[it];
            int dd = c >> 4, vs = c & 15;
            *(short8*)&Vs[dd*VSTR + vs*8] = vreg[it];
        }
        __syncthreads();

        // prefetch next tile (latency overlaps all compute below)
        if (kt + 1 < nkt) {
            const long koff = (long)(kt+1) * 128;
#pragma unroll
            for (int it = 0; it < 2; it++) {
                int c = it * 512 + tid;
                int kk = c >> 3, ks = c & 7;
                kreg[it] = *(const short8*)&Kb[(koff + kk) * DD + ks*8];
                int dd = c >> 4, vs = c & 15;
                vreg[it] = *(const short8*)&Vb[(long)dd * TT + koff + vs*8];
            }
        }

        // S^T = mfma(K, Q): col = q = l15, row = key = quad*4 + i
        float4_ s[8];
        __builtin_amdgcn_s_setprio(1);
#pragma unroll
        for (int nt = 0; nt < 8; nt++) {
            short8 bk0 = *(const short8*)&Ks[(nt*16 + l15) * KSTR + quad*8];
            short8 bk1 = *(const short8*)&Ks[(nt*16 + l15) * KSTR + 32 + quad*8];
            float4_ acc = float4_{0.f, 0.f, 0.f, 0.f};
            acc = __builtin_amdgcn_mfma_f32_16x16x32_bf16(bk0, aq0, acc, 0,0,0);
            acc = __builtin_amdgcn_mfma_f32_16x16x32_bf16(bk1, aq1, acc, 0,0,0);
            s[nt] = acc;
        }
        __builtin_amdgcn_s_setprio(0);

        if (kt == nkt - 1) {   // only the diagonal tile crosses the mask
#pragma unroll
            for (int nt = 0; nt < 8; nt++) {
#pragma unroll
                for (int i = 0; i < 4; i++) {
                    const int key = kt*128 + nt*16 + quad*4 + i;
                    if (key > qrow) s[nt][i] = -INFINITY;
                }
            }
        }

        // row max: in-register tree over this lane's 32 keys + cross-quad shfl
        float t8[8];
#pragma unroll
        for (int nt = 0; nt < 8; nt++)
            t8[nt] = fmaxf(fmaxf(s[nt][0], s[nt][1]), fmaxf(s[nt][2], s[nt][3]));
        float pm = fmaxf(fmaxf(fmaxf(t8[0], t8[1]), fmaxf(t8[2], t8[3])),
                         fmaxf(fmaxf(t8[4], t8[5]), fmaxf(t8[6], t8[7])));
        pm = fmaxf(pm, __shfl_xor(pm, 16));
        pm = fmaxf(pm, __shfl_xor(pm, 32));

        // T13 defer-max: skip rescale if max grew by < 8 (log2 domain, <=2^8)
        if (!__all(pm <= m_run + 8.0f)) {
            const float mnew = fmaxf(m_run, pm);
            const float alpha = exp2f(m_run - mnew);   // 0 on first tile
            m_run = mnew;
            l_run *= alpha;
#pragma unroll
            for (int nt = 0; nt < 4; nt++)
#pragma unroll
                for (int i = 0; i < 4; i++) o[nt][i] *= alpha;
        }

        // P = exp2(S - m) in-place (f32), accumulate row sum
        float rs0 = 0.f, rs1 = 0.f, rs2 = 0.f, rs3 = 0.f;
#pragma unroll
        for (int nt = 0; nt < 8; nt++) {
            const float p0 = exp2f(s[nt][0] - m_run);  // masked -> 0
            const float p1 = exp2f(s[nt][1] - m_run);
            const float p2 = exp2f(s[nt][2] - m_run);
            const float p3 = exp2f(s[nt][3] - m_run);
            s[nt][0] = p0; s[nt][1] = p1; s[nt][2] = p2; s[nt][3] = p3;
            rs0 += p0; rs1 += p1; rs2 += p2; rs3 += p3;
        }
        float rs = (rs0 + rs1) + (rs2 + rs3);
        rs += __shfl_xor(rs, 16);
        rs += __shfl_xor(rs, 32);
        l_run += rs;

        // O^T += V^T @ P^T, P straight from registers.
        // k-slot (quad,j) -> key (2c + (j>>2))*16 + quad*4 + (j&3); V reads
        // use the same mapping: two b64 loads per output tile.
        __builtin_amdgcn_s_setprio(1);
#pragma unroll
        for (int c = 0; c < 4; c++) {
            short8 bp;
#pragma unroll
            for (int i = 0; i < 4; i++) {
                bp[i]     = (short)f2bf(s[2*c    ][i]);
                bp[i + 4] = (short)f2bf(s[2*c + 1][i]);
            }
#pragma unroll
            for (int nt = 0; nt < 4; nt++) {
                const ushort* vrow = &Vs[(nt*16 + l15) * VSTR];
                short4_ lo = *(const short4_*)&vrow[(2*c    )*16 + quad*4];
                short4_ hi = *(const short4_*)&vrow[(2*c + 1)*16 + quad*4];
                short8 av;
                av[0]=lo[0]; av[1]=lo[1]; av[2]=lo[2]; av[3]=lo[3];
                av[4]=hi[0]; av[5]=hi[1]; av[6]=hi[2]; av[7]=hi[3];
                o[nt] = __builtin_amdgcn_mfma_f32_16x16x32_bf16(av, bp, o[nt], 0,0,0);
            }
        }
        __builtin_amdgcn_s_setprio(0);
    }

    // epilogue: AO[b, t=qrow, h*64 + d] = o / l ; d = nt*16 + quad*4 + i
    const int h = bh & (HH - 1);
    const int b = bh >> 4;
    const float inv = 1.0f / l_run;
    const long rowOff = ((long)(b*TT + qrow)) * EE + h*64;
#pragma unroll
    for (int nt = 0; nt < 4; nt++) {
        ushort4_ pk;
#pragma unroll
        for (int i = 0; i < 4; i++) pk[i] = f2bf(o[nt][i] * inv);
        *(ushort4_*)&AO[rowOff + nt*16 + quad*4] = pk;
    }
}

// ---------------------------------------------------------------------------
extern "C" void kernel_launch(void* const* d_in, const int* in_sizes, int n_in,
                              void* d_out, int out_size, void* d_ws, size_t ws_size,
                              hipStream_t stream)
{
    const float* query  = (const float*)d_in[0];
    const float* key_in = (const float*)d_in[1];
    const float* value  = (const float*)d_in[2];
    // d_in[3] = mask (int32 tril) — causal is hard-coded in flash_kernel
    const float* Wq = (const float*)d_in[4];
    const float* bq = (const float*)d_in[5];
    const float* Wk = (const float*)d_in[6];
    const float* bk = (const float*)d_in[7];
    const float* Wv = (const float*)d_in[8];
    const float* bv = (const float*)d_in[9];
    const float* Wo = (const float*)d_in[10];
    const float* bo = (const float*)d_in[11];

    ushort* ws = (ushort*)d_ws;
    const size_t NIN = (size_t)MM * KK;        // 8,388,608 elems (inputs)
    const size_t NW  = (size_t)EE * KK;        // 1,048,576 elems (weights)
    ushort* X0  = ws;                          // 16 MB cvt scratch (Q/K/V serially)
    ushort* Wqc = ws + NIN;                    // 2 MB
    ushort* Wkc = Wqc + NW;
    ushort* Wvc = Wkc + NW;
    ushort* Woc = Wvc + NW;
    ushort* Qh  = Woc + NW;                    // 16 MB  [bh][t][d], pre-scaled
    ushort* Kh  = Qh + NIN;                    // 16 MB  [bh][t][d]
    ushort* Vth = Kh + NIN;                    // 16 MB  [bh][d][t]
    ushort* AO  = X0;                          // alias: X0 dead after gemmV

    dim3 gemm_grid(EE/128, MM/128);            // 8 x 64
    const dim3 cvtW_grid(NW/1024, 4), cvtI_grid(NIN/1024, 1);

    // weights -> bf16 (batched)
    cvt_kernel<<<cvtW_grid, 256, 0, stream>>>(Wq, Wqc, (int)NW, Wk, Wkc, (int)NW,
                                              Wv, Wvc, (int)NW, Wo, Woc, (int)NW);
    // Q/K/V: cvt then project (X0 reused; stream order serializes correctly)
    cvt_kernel<<<cvtI_grid, 256, 0, stream>>>(query, X0, (int)NIN, nullptr, nullptr, 0,
                                              nullptr, nullptr, 0, nullptr, nullptr, 0);
    gemm_nt<1><<<gemm_grid, 256, 0, stream>>>(X0, Wqc, bq, Qh, 0.125f * LOG2E);
    cvt_kernel<<<cvtI_grid, 256, 0, stream>>>(key_in, X0, (int)NIN, nullptr, nullptr, 0,
                                              nullptr, nullptr, 0, nullptr, nullptr, 0);
    gemm_nt<1><<<gemm_grid, 256, 0, stream>>>(X0, Wkc, bk, Kh, 1.0f);
    cvt_kernel<<<cvtI_grid, 256, 0, stream>>>(value, X0, (int)NIN, nullptr, nullptr, 0,
                                              nullptr, nullptr, 0, nullptr, nullptr, 0);
    gemm_nt<2><<<gemm_grid, 256, 0, stream>>>(X0, Wvc, bv, Vth, 1.0f);

    flash_kernel<<<dim3(TT/128, BH), 512, 0, stream>>>(Qh, Kh, Vth, AO);
    gemm_nt<0><<<gemm_grid, 256, 0, stream>>>(AO, Woc, bo, d_out, 1.0f);
}

// Round 3
// 421.302 us; speedup vs baseline: 1.5885x; 1.5885x over previous
//
#include <hip/hip_runtime.h>
#include <hip/hip_bf16.h>
#include <cstdint>

// Problem constants
#define BB 4
#define TT 2048
#define EE 1024
#define HH 16
#define DD 64
#define BH (BB*HH)       // 64
#define MM (BB*TT)       // 8192 rows for projection GEMMs
#define KK 1024          // contraction dim for projections
#define KSTR 72          // flash K-tile LDS row stride (ushorts)
#define VSTR 136         // flash V-tile LDS row stride (ushorts)
#define LOG2E 1.44269504088896340736f

typedef __attribute__((ext_vector_type(8))) short short8;    // 8 x bf16
typedef __attribute__((ext_vector_type(4))) short short4_;   // 4 x bf16
typedef __attribute__((ext_vector_type(4))) float float4_;   // MFMA accumulator
typedef __attribute__((ext_vector_type(4))) ushort ushort4_;

__device__ __forceinline__ void gl_lds16(const void* g, void* l) {
    __builtin_amdgcn_global_load_lds(
        (const __attribute__((address_space(1))) void*)g,
        (__attribute__((address_space(3))) void*)l, 16, 0, 0);
}

__device__ __forceinline__ ushort f2bf(float v) {
    __hip_bfloat16 h = __float2bfloat16(v);
    return *(ushort*)&h;
}

// ---------------------------------------------------------------------------
// fp32 -> bf16 conversion. grid.y selects segment (ptr,n); oversized grid.x
// blocks for short segments exit early.
// ---------------------------------------------------------------------------
__global__ __launch_bounds__(256) void cvt_kernel(
    const float* __restrict__ s0, ushort* __restrict__ d0, int n0,
    const float* __restrict__ s1, ushort* __restrict__ d1, int n1,
    const float* __restrict__ s2, ushort* __restrict__ d2, int n2,
    const float* __restrict__ s3, ushort* __restrict__ d3, int n3)
{
    const float* s; ushort* d; int n;
    switch (blockIdx.y) {
        case 0: s = s0; d = d0; n = n0; break;
        case 1: s = s1; d = d1; n = n1; break;
        case 2: s = s2; d = d2; n = n2; break;
        default: s = s3; d = d3; n = n3; break;
    }
    int i = (blockIdx.x * 256 + threadIdx.x) * 4;
    if (i >= n) return;
    float4_ v = *(const float4_*)&s[i];
    ushort4_ o;
#pragma unroll
    for (int j = 0; j < 4; j++) o[j] = f2bf(v[j]);
    *(ushort4_*)&d[i] = o;
}

// ---------------------------------------------------------------------------
// Pure-bf16 NT GEMM (m97 structure): C[n,e] = (sum_k A[n,k]*W[e,k] + bias[e])*scale
// MODE 0: C fp32 row-major [MM, EE]
// MODE 1: scatter bf16 per-head [B*H, T, D]
// MODE 2: scatter bf16 per-head transposed [B*H, D, T] (packed 8B stores)
// 128x128 tile, BK=32, 256 threads (4 waves, 2x2 of 64x64).
// ---------------------------------------------------------------------------
template<int MODE>
__global__ __launch_bounds__(256, 3) void gemm_nt(
    const ushort* __restrict__ A, const ushort* __restrict__ W,
    const float* __restrict__ bias, void* __restrict__ Cout, float scale)
{
    __shared__ __align__(16) ushort As[128*32];
    __shared__ __align__(16) ushort Bs[128*32];

    const int tid  = threadIdx.x;
    const int wave = tid >> 6;
    const int lane = tid & 63;
    const int l15  = lane & 15;
    const int quad = lane >> 4;
    const int wm   = wave & 1;   // row half
    const int wn   = wave >> 1;  // col half

    const long rowBase = (long)blockIdx.y * 128;
    const long colBase = (long)blockIdx.x * 128;

    float4_ acc[4][4];
#pragma unroll
    for (int i = 0; i < 4; i++)
#pragma unroll
        for (int j = 0; j < 4; j++) acc[i][j] = float4_{0.f, 0.f, 0.f, 0.f};

    for (int k0 = 0; k0 < KK; k0 += 32) {
        __syncthreads();
#pragma unroll
        for (int it = 0; it < 2; it++) {
            int idx = it * 256 + tid;          // 0..511
            int r   = idx >> 2;                // tile row 0..127
            int c8  = (idx & 3) * 8;           // k chunk (8 bf16 = 16B)
            gl_lds16(A + (rowBase + r) * KK + k0 + c8, &As[idx * 8]);
            gl_lds16(W + (colBase + r) * KK + k0 + c8, &Bs[idx * 8]);
        }
        __syncthreads();

        short8 af[4], bf[4];
#pragma unroll
        for (int mt = 0; mt < 4; mt++)
            af[mt] = *(const short8*)&As[(wm*64 + mt*16 + l15) * 32 + quad*8];
#pragma unroll
        for (int nt = 0; nt < 4; nt++)
            bf[nt] = *(const short8*)&Bs[(wn*64 + nt*16 + l15) * 32 + quad*8];
#pragma unroll
        for (int mt = 0; mt < 4; mt++)
#pragma unroll
            for (int nt = 0; nt < 4; nt++)
                acc[mt][nt] = __builtin_amdgcn_mfma_f32_16x16x32_bf16(
                    af[mt], bf[nt], acc[mt][nt], 0, 0, 0);
    }

    // Epilogue: C/D layout col = lane&15, row = quad*4 + reg
#pragma unroll
    for (int nt = 0; nt < 4; nt++) {
        const long col = colBase + wn*64 + nt*16 + l15;
        const float bv = bias[col];
#pragma unroll
        for (int mt = 0; mt < 4; mt++) {
            const long row0 = rowBase + wm*64 + mt*16 + quad*4;
            if (MODE == 2) {
                const long h = col >> 6, d = col & (DD - 1);
                const long b = row0 >> 11, t0 = row0 & (TT - 1);
                ushort4_ pk;
#pragma unroll
                for (int i = 0; i < 4; i++) pk[i] = f2bf((acc[mt][nt][i] + bv) * scale);
                *(ushort4_*)((ushort*)Cout + ((b*HH + h)*DD + d)*TT + t0) = pk;
            } else {
#pragma unroll
                for (int i = 0; i < 4; i++) {
                    const long row = row0 + i;
                    const float v = (acc[mt][nt][i] + bv) * scale;
                    if (MODE == 0) {
                        ((float*)Cout)[row * EE + col] = v;
                    } else {
                        const long b = row >> 11, t = row & (TT - 1);
                        const long h = col >> 6,  d = col & (DD - 1);
                        ((ushort*)Cout)[(((b*HH + h) * TT) + t) * DD + d] = f2bf(v);
                    }
                }
            }
        }
    }
}

// ---------------------------------------------------------------------------
// Flash attention (causal). Q,K: [B*H, T, D] bf16; Vt: [B*H, D, T] bf16;
// AO: [B, T, E] bf16.  Q pre-scaled by 0.125*log2(e) -> softmax via exp2.
//
// Operand-swapped layout: S^T = mfma(K, Q) -> lane owns 32 keys of ONE q-row
// (scalar softmax state, 2 shfls per reduction).  P stays in registers: the
// PV k-slot -> key mapping (chunk c covers keys nt in {2c,2c+1}, k-slot
// (quad,j) -> key (2c + (j>>2))*16 + quad*4 + (j&3)) makes the P B-frag a
// pure register repack and the V A-frag two ds_read_b64 per output tile.
// No Ps buffer -> LDS 35.8 KB, no P round-trip/fence on the serial path.
//
// Round-3 fixes (round 2 spilled): launch_bounds back to (512,4) — the
// (512,8) cap forced VGPR<=64 and the compiler spilled s[]/o[] to scratch
// (FETCH 547 MB, WRITE 660 MB of spill traffic, 2.5x slowdown).  Also pack
// P to bf16 INSIDE the exp2 loop (pb[4], 16 VGPR) so the f32 s[8] (32 VGPR)
// dies before the PV phase — peak live set now fits the 128-reg cap.
// ---------------------------------------------------------------------------
__global__ __launch_bounds__(512, 4) void flash_kernel(
    const ushort* __restrict__ Qh, const ushort* __restrict__ Kh,
    const ushort* __restrict__ Vt, ushort* __restrict__ AO)
{
    __shared__ __align__(16) ushort Ks[128*KSTR];    // [key][d]     18.4 KB
    __shared__ __align__(16) ushort Vs[64*VSTR];     // [d][key]     17.4 KB

    const int qt  = (TT/128 - 1) - blockIdx.x;  // heavy tiles dispatch first
    const int bh  = blockIdx.y;                 // b*H + h
    const int tid = threadIdx.x;
    const int wave = tid >> 6, lane = tid & 63;
    const int l15 = lane & 15, quad = lane >> 4;

    const ushort* Qb = Qh + (long)bh * TT * DD;
    const ushort* Kb = Kh + (long)bh * TT * DD;
    const ushort* Vb = Vt + (long)bh * DD * TT;

    // This lane's q-row (B-fragment of swapped QK^T; also the output t)
    const int qrow = qt*128 + wave*16 + l15;
    short8 aq0 = *(const short8*)&Qb[(long)qrow * DD + quad*8];
    short8 aq1 = *(const short8*)&Qb[(long)qrow * DD + 32 + quad*8];

    // O^T accumulator: o[nt][i] = O[q=qrow][d = nt*16 + quad*4 + i]
    float4_ o[4];
#pragma unroll
    for (int nt = 0; nt < 4; nt++) o[nt] = float4_{0.f, 0.f, 0.f, 0.f};
    float m_run = -INFINITY, l_run = 0.0f;      // scalar per lane (one q-row)

    const int nkt = qt + 1;                    // number of 128-key tiles

    // prefetch tile 0 into registers (K: 128x64, V^T: 64x128)
    short8 kreg[2], vreg[2];
#pragma unroll
    for (int it = 0; it < 2; it++) {
        int c = it * 512 + tid;                    // 0..1023
        int kk = c >> 3, ks = c & 7;               // K: key, 16B seg
        kreg[it] = *(const short8*)&Kb[(long)kk * DD + ks*8];
        int dd = c >> 4, vs = c & 15;              // V: d, 16B seg
        vreg[it] = *(const short8*)&Vb[(long)dd * TT + vs*8];
    }

    for (int kt = 0; kt < nkt; kt++) {
        __syncthreads();   // previous tile's LDS reads done
#pragma unroll
        for (int it = 0; it < 2; it++) {
            int c = it * 512 + tid;
            int kk = c >> 3, ks = c & 7;
            *(short8*)&Ks[kk*KSTR + ks*8] = kreg[it];
            int dd = c >> 4, vs = c & 15;
            *(short8*)&Vs[dd*VSTR + vs*8] = vreg[it];
        }
        __syncthreads();

        // prefetch next tile (latency overlaps all compute below)
        if (kt + 1 < nkt) {
            const long koff = (long)(kt+1) * 128;
#pragma unroll
            for (int it = 0; it < 2; it++) {
                int c = it * 512 + tid;
                int kk = c >> 3, ks = c & 7;
                kreg[it] = *(const short8*)&Kb[(koff + kk) * DD + ks*8];
                int dd = c >> 4, vs = c & 15;
                vreg[it] = *(const short8*)&Vb[(long)dd * TT + koff + vs*8];
            }
        }

        // S^T = mfma(K, Q): col = q = l15, row = key = quad*4 + i
        float4_ s[8];
        __builtin_amdgcn_s_setprio(1);
#pragma unroll
        for (int nt = 0; nt < 8; nt++) {
            short8 bk0 = *(const short8*)&Ks[(nt*16 + l15) * KSTR + quad*8];
            short8 bk1 = *(const short8*)&Ks[(nt*16 + l15) * KSTR + 32 + quad*8];
            float4_ acc = float4_{0.f, 0.f, 0.f, 0.f};
            acc = __builtin_amdgcn_mfma_f32_16x16x32_bf16(bk0, aq0, acc, 0,0,0);
            acc = __builtin_amdgcn_mfma_f32_16x16x32_bf16(bk1, aq1, acc, 0,0,0);
            s[nt] = acc;
        }
        __builtin_amdgcn_s_setprio(0);

        if (kt == nkt - 1) {   // only the diagonal tile crosses the mask
#pragma unroll
            for (int nt = 0; nt < 8; nt++) {
#pragma unroll
                for (int i = 0; i < 4; i++) {
                    const int key = kt*128 + nt*16 + quad*4 + i;
                    if (key > qrow) s[nt][i] = -INFINITY;
                }
            }
        }

        // row max: in-register tree over this lane's 32 keys + cross-quad shfl
        float t8[8];
#pragma unroll
        for (int nt = 0; nt < 8; nt++)
            t8[nt] = fmaxf(fmaxf(s[nt][0], s[nt][1]), fmaxf(s[nt][2], s[nt][3]));
        float pm = fmaxf(fmaxf(fmaxf(t8[0], t8[1]), fmaxf(t8[2], t8[3])),
                         fmaxf(fmaxf(t8[4], t8[5]), fmaxf(t8[6], t8[7])));
        pm = fmaxf(pm, __shfl_xor(pm, 16));
        pm = fmaxf(pm, __shfl_xor(pm, 32));

        // T13 defer-max: skip rescale if max grew by < 8 (log2 domain, <=2^8)
        if (!__all(pm <= m_run + 8.0f)) {
            const float mnew = fmaxf(m_run, pm);
            const float alpha = exp2f(m_run - mnew);   // 0 on first tile
            m_run = mnew;
            l_run *= alpha;
#pragma unroll
            for (int nt = 0; nt < 4; nt++)
#pragma unroll
                for (int i = 0; i < 4; i++) o[nt][i] *= alpha;
        }

        // P = exp2(S - m): accumulate row sum and pack to bf16 IMMEDIATELY
        // (pb[4] = 16 VGPRs replaces live f32 s[8] = 32 VGPRs in PV phase)
        float rs0 = 0.f, rs1 = 0.f, rs2 = 0.f, rs3 = 0.f;
        short8 pb[4];
#pragma unroll
        for (int c = 0; c < 4; c++) {
#pragma unroll
            for (int half = 0; half < 2; half++) {
                const int nt = 2*c + half;
                const float p0 = exp2f(s[nt][0] - m_run);  // masked -> 0
                const float p1 = exp2f(s[nt][1] - m_run);
                const float p2 = exp2f(s[nt][2] - m_run);
                const float p3 = exp2f(s[nt][3] - m_run);
                rs0 += p0; rs1 += p1; rs2 += p2; rs3 += p3;
                pb[c][half*4 + 0] = (short)f2bf(p0);
                pb[c][half*4 + 1] = (short)f2bf(p1);
                pb[c][half*4 + 2] = (short)f2bf(p2);
                pb[c][half*4 + 3] = (short)f2bf(p3);
            }
        }
        float rs = (rs0 + rs1) + (rs2 + rs3);
        rs += __shfl_xor(rs, 16);
        rs += __shfl_xor(rs, 32);
        l_run += rs;

        // O^T += V^T @ P^T, P straight from registers.
        // k-slot (quad,j) -> key (2c + (j>>2))*16 + quad*4 + (j&3); V reads
        // use the same mapping: two b64 loads per output tile.
        __builtin_amdgcn_s_setprio(1);
#pragma unroll
        for (int c = 0; c < 4; c++) {
            const short8 bp = pb[c];
#pragma unroll
            for (int nt = 0; nt < 4; nt++) {
                const ushort* vrow = &Vs[(nt*16 + l15) * VSTR];
                short4_ lo = *(const short4_*)&vrow[(2*c    )*16 + quad*4];
                short4_ hi = *(const short4_*)&vrow[(2*c + 1)*16 + quad*4];
                short8 av;
                av[0]=lo[0]; av[1]=lo[1]; av[2]=lo[2]; av[3]=lo[3];
                av[4]=hi[0]; av[5]=hi[1]; av[6]=hi[2]; av[7]=hi[3];
                o[nt] = __builtin_amdgcn_mfma_f32_16x16x32_bf16(av, bp, o[nt], 0,0,0);
            }
        }
        __builtin_amdgcn_s_setprio(0);
    }

    // epilogue: AO[b, t=qrow, h*64 + d] = o / l ; d = nt*16 + quad*4 + i
    const int h = bh & (HH - 1);
    const int b = bh >> 4;
    const float inv = 1.0f / l_run;
    const long rowOff = ((long)(b*TT + qrow)) * EE + h*64;
#pragma unroll
    for (int nt = 0; nt < 4; nt++) {
        ushort4_ pk;
#pragma unroll
        for (int i = 0; i < 4; i++) pk[i] = f2bf(o[nt][i] * inv);
        *(ushort4_*)&AO[rowOff + nt*16 + quad*4] = pk;
    }
}

// ---------------------------------------------------------------------------
extern "C" void kernel_launch(void* const* d_in, const int* in_sizes, int n_in,
                              void* d_out, int out_size, void* d_ws, size_t ws_size,
                              hipStream_t stream)
{
    const float* query  = (const float*)d_in[0];
    const float* key_in = (const float*)d_in[1];
    const float* value  = (const float*)d_in[2];
    // d_in[3] = mask (int32 tril) — causal is hard-coded in flash_kernel
    const float* Wq = (const float*)d_in[4];
    const float* bq = (const float*)d_in[5];
    const float* Wk = (const float*)d_in[6];
    const float* bk = (const float*)d_in[7];
    const float* Wv = (const float*)d_in[8];
    const float* bv = (const float*)d_in[9];
    const float* Wo = (const float*)d_in[10];
    const float* bo = (const float*)d_in[11];

    ushort* ws = (ushort*)d_ws;
    const size_t NIN = (size_t)MM * KK;        // 8,388,608 elems (inputs)
    const size_t NW  = (size_t)EE * KK;        // 1,048,576 elems (weights)
    ushort* X0  = ws;                          // 16 MB cvt scratch (Q/K/V serially)
    ushort* Wqc = ws + NIN;                    // 2 MB
    ushort* Wkc = Wqc + NW;
    ushort* Wvc = Wkc + NW;
    ushort* Woc = Wvc + NW;
    ushort* Qh  = Woc + NW;                    // 16 MB  [bh][t][d], pre-scaled
    ushort* Kh  = Qh + NIN;                    // 16 MB  [bh][t][d]
    ushort* Vth = Kh + NIN;                    // 16 MB  [bh][d][t]
    ushort* AO  = X0;                          // alias: X0 dead after gemmV

    dim3 gemm_grid(EE/128, MM/128);            // 8 x 64
    const dim3 cvtW_grid(NW/1024, 4), cvtI_grid(NIN/1024, 1);

    // weights -> bf16 (batched)
    cvt_kernel<<<cvtW_grid, 256, 0, stream>>>(Wq, Wqc, (int)NW, Wk, Wkc, (int)NW,
                                              Wv, Wvc, (int)NW, Wo, Woc, (int)NW);
    // Q/K/V: cvt then project (X0 reused; stream order serializes correctly)
    cvt_kernel<<<cvtI_grid, 256, 0, stream>>>(query, X0, (int)NIN, nullptr, nullptr, 0,
                                              nullptr, nullptr, 0, nullptr, nullptr, 0);
    gemm_nt<1><<<gemm_grid, 256, 0, stream>>>(X0, Wqc, bq, Qh, 0.125f * LOG2E);
    cvt_kernel<<<cvtI_grid, 256, 0, stream>>>(key_in, X0, (int)NIN, nullptr, nullptr, 0,
                                              nullptr, nullptr, 0, nullptr, nullptr, 0);
    gemm_nt<1><<<gemm_grid, 256, 0, stream>>>(X0, Wkc, bk, Kh, 1.0f);
    cvt_kernel<<<cvtI_grid, 256, 0, stream>>>(value, X0, (int)NIN, nullptr, nullptr, 0,
                                              nullptr, nullptr, 0, nullptr, nullptr, 0);
    gemm_nt<2><<<gemm_grid, 256, 0, stream>>>(X0, Wvc, bv, Vth, 1.0f);

    flash_kernel<<<dim3(TT/128, BH), 512, 0, stream>>>(Qh, Kh, Vth, AO);
    gemm_nt<0><<<gemm_grid, 256, 0, stream>>>(AO, Woc, bo, d_out, 1.0f);
}